// Round 1
// baseline (1894.458 us; speedup 1.0000x reference)
//
#include <hip/hip_runtime.h>
#include <cstdint>
#include <cstddef>

// ---- problem constants ----
#define NTOK 16384     // B*S = 4*4096
#define HIDN 2048
#define NH   16
#define HD   128
#define NB   4
#define EPSF 1e-6f

typedef __attribute__((ext_vector_type(8))) short bvec8;   // 8 bf16 (4 VGPRs)
typedef __attribute__((ext_vector_type(4))) float fvec4;   // MFMA accumulator

__device__ __forceinline__ unsigned short f2bf(float x) {
  union { float f; uint32_t u; } v; v.f = x;
  uint32_t r = (v.u + 0x7fffu + ((v.u >> 16) & 1u)) >> 16;  // RNE
  return (unsigned short)r;
}
__device__ __forceinline__ float bf2f(unsigned short b) {
  union { uint32_t u; float f; } v; v.u = ((uint32_t)b) << 16;
  return v.f;
}
__device__ __forceinline__ float elu1(float x) { return x > 0.f ? x + 1.f : __expf(x); }

// ---- K0: softmax(bank_weights)*active -> wact[h*4+n] ----
__global__ void prep_kernel(const float* __restrict__ bw, const float* __restrict__ mnorm,
                            float* __restrict__ wact) {
  __shared__ float act[NB];
  int tid = threadIdx.x;  // 64 threads
  if (tid < NB) {
    float s = 0.f;
    for (int i = 0; i < NH * HD; i++) s += mnorm[tid * NH * HD + i];
    act[tid] = (s >= EPSF) ? 1.f : 0.f;
  }
  __syncthreads();
  int h = tid >> 2, n = tid & 3;
  float w0 = bw[h*4+0], w1 = bw[h*4+1], w2 = bw[h*4+2], w3 = bw[h*4+3];
  float mx = fmaxf(fmaxf(w0, w1), fmaxf(w2, w3));
  float e0 = __expf(w0-mx), e1 = __expf(w1-mx), e2 = __expf(w2-mx), e3 = __expf(w3-mx);
  float sum = e0 + e1 + e2 + e3;
  float en = (n == 0) ? e0 : ((n == 1) ? e1 : ((n == 2) ? e2 : e3));
  wact[tid] = (en / sum) * act[n];
}

// ---- K1: fp32 -> bf16 cast, 8 elems/thread ----
__global__ __launch_bounds__(256) void cast_bf16_kernel(const float* __restrict__ src,
                                                        unsigned short* __restrict__ dst, int n8) {
  int i = blockIdx.x * 256 + threadIdx.x;
  if (i >= n8) return;
  const float4* s = (const float4*)src + (size_t)i * 2;
  float4 a = s[0], b = s[1];
  uint32_t p0 = (uint32_t)f2bf(a.x) | ((uint32_t)f2bf(a.y) << 16);
  uint32_t p1 = (uint32_t)f2bf(a.z) | ((uint32_t)f2bf(a.w) << 16);
  uint32_t p2 = (uint32_t)f2bf(b.x) | ((uint32_t)f2bf(b.y) << 16);
  uint32_t p3 = (uint32_t)f2bf(b.z) | ((uint32_t)f2bf(b.w) << 16);
  uint4 o; o.x = p0; o.y = p1; o.z = p2; o.w = p3;
  *(uint4*)(dst + (size_t)i * 8) = o;
}

// ---- K1b: memories[n,h,d,e] -> bf16 transposed membT[n,h,e,d] ----
__global__ __launch_bounds__(256) void mem_transpose_kernel(const float* __restrict__ mem,
                                                            unsigned short* __restrict__ membT) {
  int nh = blockIdx.x;  // 64 blocks
  const float* src = mem + (size_t)nh * (HD * HD);
  unsigned short* dst = membT + (size_t)nh * (HD * HD);
  for (int i = threadIdx.x; i < HD * HD; i += 256) {
    int d = i >> 7, e = i & 127;
    dst[e * HD + d] = f2bf(src[i]);
  }
}

// ---- K2/K11: NT GEMM, 128x128 tile, BK=32, 4 waves (2x2), 16x16x32 bf16 MFMA ----
// C[i,j] = sum_k A[i,k]*B[j,k].  MODE 0: QKV epilogue (elu+1 on q,k; bf16 out to 3 bufs)
//                                MODE 1: fp32 C out (ld = N)
template<int MODE>
__global__ __launch_bounds__(256) void gemm_nt_kernel(
    const unsigned short* __restrict__ A, const unsigned short* __restrict__ B,
    int K, int N,
    unsigned short* __restrict__ oq, unsigned short* __restrict__ ok,
    unsigned short* __restrict__ ov, float* __restrict__ oc) {
  __shared__ unsigned short As[128 * 40];  // 32 k + 8 pad (2-way bank alias = free)
  __shared__ unsigned short Bs[128 * 40];
  const int tid = threadIdx.x;
  const int wave = tid >> 6, lane = tid & 63;
  const int lr = lane & 15, lq = lane >> 4;
  const int wr = (wave >> 1) * 64, wc = (wave & 1) * 64;
  const int bm = blockIdx.x, bn = blockIdx.y;
  const size_t arow0 = (size_t)bm * 128;
  const size_t brow0 = (size_t)bn * 128;
  fvec4 acc[4][4] = {};
  for (int k0 = 0; k0 < K; k0 += 32) {
    __syncthreads();
#pragma unroll
    for (int p = 0; p < 2; p++) {
      int c = tid + p * 256;
      int row = c >> 2, kc = (c & 3) * 8;
      *(uint4*)(As + row * 40 + kc) = *(const uint4*)(A + (arow0 + row) * K + k0 + kc);
      *(uint4*)(Bs + row * 40 + kc) = *(const uint4*)(B + (brow0 + row) * K + k0 + kc);
    }
    __syncthreads();
    bvec8 af[4], bfr[4];
#pragma unroll
    for (int mi = 0; mi < 4; mi++)
      af[mi] = *(const bvec8*)(As + (wr + mi * 16 + lr) * 40 + lq * 8);
#pragma unroll
    for (int ni = 0; ni < 4; ni++)
      bfr[ni] = *(const bvec8*)(Bs + (wc + ni * 16 + lr) * 40 + lq * 8);
#pragma unroll
    for (int mi = 0; mi < 4; mi++)
#pragma unroll
      for (int ni = 0; ni < 4; ni++)
        acc[mi][ni] = __builtin_amdgcn_mfma_f32_16x16x32_bf16(af[mi], bfr[ni], acc[mi][ni], 0, 0, 0);
  }
  // epilogue: D row = (lane>>4)*4 + reg, col = lane&15  [measured m89/m91]
#pragma unroll
  for (int mi = 0; mi < 4; mi++) {
#pragma unroll
    for (int ni = 0; ni < 4; ni++) {
#pragma unroll
      for (int r = 0; r < 4; r++) {
        int grow = bm * 128 + wr + mi * 16 + lq * 4 + r;
        int gcol = bn * 128 + wc + ni * 16 + lr;
        float v = acc[mi][ni][r];
        if (MODE == 0) {
          int seg = gcol >> 11;  // 0:q 1:k 2:v
          int col = gcol & 2047;
          unsigned short* dst = (seg == 0) ? oq : ((seg == 1) ? ok : ov);
          float t = (seg < 2) ? elu1(v) : v;
          dst[(size_t)grow * HIDN + col] = f2bf(t);
        } else {
          oc[(size_t)grow * N + gcol] = v;
        }
      }
    }
  }
}

// ---- K5: per-(token,head) bank coefficients + knorm ----
__global__ __launch_bounds__(256) void coeff_kernel(
    const unsigned short* __restrict__ sq, const unsigned short* __restrict__ sk,
    const float* __restrict__ mnorm, const float* __restrict__ wact,
    float* __restrict__ cbuf, float* __restrict__ knorm) {
  int g = blockIdx.x * 256 + threadIdx.x;  // 262144 = T*NH
  int t = g >> 4, h = g & 15;
  const unsigned short* qp = sq + (size_t)t * HIDN + h * HD;
  const unsigned short* kp = sk + (size_t)t * HIDN + h * HD;
  const float* m0 = mnorm + (0 * NH + h) * HD;
  const float* m1 = mnorm + (1 * NH + h) * HD;
  const float* m2 = mnorm + (2 * NH + h) * HD;
  const float* m3 = mnorm + (3 * NH + h) * HD;
  float n0 = 0, n1 = 0, n2 = 0, n3 = 0, kn = 0;
  for (int i = 0; i < HD; i++) {
    float qv = bf2f(qp[i]);
    float kv = bf2f(kp[i]);
    n0 += qv * m0[i]; n1 += qv * m1[i]; n2 += qv * m2[i]; n3 += qv * m3[i];
    kn += kv * m0[i];
  }
  cbuf[(size_t)g * 4 + 0] = wact[h * 4 + 0] / fmaxf(n0, EPSF);
  cbuf[(size_t)g * 4 + 1] = wact[h * 4 + 1] / fmaxf(n1, EPSF);
  cbuf[(size_t)g * 4 + 2] = wact[h * 4 + 2] / fmaxf(n2, EPSF);
  cbuf[(size_t)g * 4 + 3] = wact[h * 4 + 3] / fmaxf(n3, EPSF);
  knorm[g] = fmaxf(kn, EPSF);
}

// ---- K6: retrieval. block = (64-token tile, head); 4 banks, scale by c, sum -> combined ----
__global__ __launch_bounds__(256) void retrieve_kernel(
    const unsigned short* __restrict__ sq, const unsigned short* __restrict__ membT,
    const float* __restrict__ cbuf, unsigned short* __restrict__ comb) {
  __shared__ unsigned short Sq[64 * 136];
  __shared__ unsigned short Mt[128 * 136];
  __shared__ float ct[64 * 4];
  const int tb = blockIdx.x, h = blockIdx.y;
  const int tid = threadIdx.x;
  const int wave = tid >> 6, lane = tid & 63;
  const int lr = lane & 15, lq = lane >> 4;
  const int wr = (wave >> 1) * 32, wc = (wave & 1) * 64;
#pragma unroll
  for (int p = 0; p < 4; p++) {  // stage Sq: 64 x 128
    int c = tid + p * 256;
    int row = c >> 4, col = (c & 15) * 8;
    *(uint4*)(Sq + row * 136 + col) =
        *(const uint4*)(sq + (size_t)(tb * 64 + row) * HIDN + h * HD + col);
  }
  {
    int tl = tid >> 2, n = tid & 3;
    ct[tid] = cbuf[(((size_t)(tb * 64 + tl)) * NH + h) * 4 + n];
  }
  float wacc[2][4][4] = {};
  for (int n = 0; n < NB; n++) {
    __syncthreads();  // prior-bank reads done (and staging visible on n=0)
    const unsigned short* msrc = membT + (size_t)(n * NH + h) * (HD * HD);
#pragma unroll
    for (int p = 0; p < 8; p++) {  // stage Mt[e][d]: 128 x 128
      int c = tid + p * 256;
      int row = c >> 4, col = (c & 15) * 8;
      *(uint4*)(Mt + row * 136 + col) = *(const uint4*)(msrc + row * HD + col);
    }
    __syncthreads();
    fvec4 u[2][4] = {};
#pragma unroll
    for (int dk = 0; dk < HD; dk += 32) {
      bvec8 af[2], bfr[4];
#pragma unroll
      for (int mi = 0; mi < 2; mi++)
        af[mi] = *(const bvec8*)(Sq + (wr + mi * 16 + lr) * 136 + dk + lq * 8);
#pragma unroll
      for (int ni = 0; ni < 4; ni++)
        bfr[ni] = *(const bvec8*)(Mt + (wc + ni * 16 + lr) * 136 + dk + lq * 8);
#pragma unroll
      for (int mi = 0; mi < 2; mi++)
#pragma unroll
        for (int ni = 0; ni < 4; ni++)
          u[mi][ni] = __builtin_amdgcn_mfma_f32_16x16x32_bf16(af[mi], bfr[ni], u[mi][ni], 0, 0, 0);
    }
#pragma unroll
    for (int mi = 0; mi < 2; mi++)
#pragma unroll
      for (int ni = 0; ni < 4; ni++)
#pragma unroll
        for (int r = 0; r < 4; r++) {
          int rl = wr + mi * 16 + lq * 4 + r;
          wacc[mi][ni][r] += ct[rl * 4 + n] * u[mi][ni][r];
        }
  }
#pragma unroll
  for (int mi = 0; mi < 2; mi++)
#pragma unroll
    for (int ni = 0; ni < 4; ni++)
#pragma unroll
      for (int r = 0; r < 4; r++) {
        int rl = wr + mi * 16 + lq * 4 + r;
        int col = h * HD + wc + ni * 16 + lr;
        comb[(size_t)(tb * 64 + rl) * HIDN + col] = f2bf(wacc[mi][ni][r]);
      }
}

// ---- K7: delta_v = v - (sigma_k @ mem0)/knorm, bf16 out ----
__global__ __launch_bounds__(256) void delta_kernel(
    const unsigned short* __restrict__ sk, const unsigned short* __restrict__ membT,
    const unsigned short* __restrict__ vb, const float* __restrict__ knorm,
    unsigned short* __restrict__ dv) {
  __shared__ unsigned short Sk[64 * 136];
  __shared__ unsigned short Mt[128 * 136];
  const int tb = blockIdx.x, h = blockIdx.y;
  const int tid = threadIdx.x;
  const int wave = tid >> 6, lane = tid & 63;
  const int lr = lane & 15, lq = lane >> 4;
  const int wr = (wave >> 1) * 32, wc = (wave & 1) * 64;
#pragma unroll
  for (int p = 0; p < 4; p++) {
    int c = tid + p * 256;
    int row = c >> 4, col = (c & 15) * 8;
    *(uint4*)(Sk + row * 136 + col) =
        *(const uint4*)(sk + (size_t)(tb * 64 + row) * HIDN + h * HD + col);
  }
  const unsigned short* msrc = membT + (size_t)h * (HD * HD);  // bank 0
#pragma unroll
  for (int p = 0; p < 8; p++) {
    int c = tid + p * 256;
    int row = c >> 4, col = (c & 15) * 8;
    *(uint4*)(Mt + row * 136 + col) = *(const uint4*)(msrc + row * HD + col);
  }
  __syncthreads();
  fvec4 u[2][4] = {};
#pragma unroll
  for (int dk = 0; dk < HD; dk += 32) {
    bvec8 af[2], bfr[4];
#pragma unroll
    for (int mi = 0; mi < 2; mi++)
      af[mi] = *(const bvec8*)(Sk + (wr + mi * 16 + lr) * 136 + dk + lq * 8);
#pragma unroll
    for (int ni = 0; ni < 4; ni++)
      bfr[ni] = *(const bvec8*)(Mt + (wc + ni * 16 + lr) * 136 + dk + lq * 8);
#pragma unroll
    for (int mi = 0; mi < 2; mi++)
#pragma unroll
      for (int ni = 0; ni < 4; ni++)
        u[mi][ni] = __builtin_amdgcn_mfma_f32_16x16x32_bf16(af[mi], bfr[ni], u[mi][ni], 0, 0, 0);
  }
#pragma unroll
  for (int mi = 0; mi < 2; mi++)
#pragma unroll
    for (int ni = 0; ni < 4; ni++)
#pragma unroll
      for (int r = 0; r < 4; r++) {
        int rl = wr + mi * 16 + lq * 4 + r;
        int t = tb * 64 + rl;
        int e = wc + ni * 16 + lr;
        float kn = knorm[(size_t)t * NH + h];
        float vv = bf2f(vb[(size_t)t * HIDN + h * HD + e]);
        dv[(size_t)t * HIDN + h * HD + e] = f2bf(vv - u[mi][ni][r] / kn);
      }
}

// ---- K8: mem_update partial: upd[h,d,e] += sum_t sigma_k[t,d]*dv[t,e] (split-K, atomics) ----
__global__ __launch_bounds__(256) void memupd_kernel(const unsigned short* __restrict__ sk,
                                                     const unsigned short* __restrict__ dv,
                                                     float* __restrict__ upd) {
  const int h = blockIdx.x, kc = blockIdx.y;  // 16 x 32, 512 tokens per chunk
  __shared__ float sA[8][128], sB[8][128];
  const int tid = threadIdx.x;
  const int tr = tid >> 4, tc = tid & 15;  // thread owns d in [tr*8,+8), e in [tc*8,+8)
  float acc[8][8] = {};
  for (int t0 = kc * 512; t0 < kc * 512 + 512; t0 += 8) {
    __syncthreads();
    int row = tid >> 5, col = (tid & 31) * 4;
    const unsigned short* ap = sk + (size_t)(t0 + row) * HIDN + h * HD + col;
    const unsigned short* bp = dv + (size_t)(t0 + row) * HIDN + h * HD + col;
    ushort4 av = *(const ushort4*)ap;
    ushort4 bv = *(const ushort4*)bp;
    sA[row][col + 0] = bf2f(av.x); sA[row][col + 1] = bf2f(av.y);
    sA[row][col + 2] = bf2f(av.z); sA[row][col + 3] = bf2f(av.w);
    sB[row][col + 0] = bf2f(bv.x); sB[row][col + 1] = bf2f(bv.y);
    sB[row][col + 2] = bf2f(bv.z); sB[row][col + 3] = bf2f(bv.w);
    __syncthreads();
#pragma unroll
    for (int tt = 0; tt < 8; tt++) {
      float a[8], b[8];
#pragma unroll
      for (int i = 0; i < 8; i++) a[i] = sA[tt][tr * 8 + i];
#pragma unroll
      for (int j = 0; j < 8; j++) b[j] = sB[tt][tc * 8 + j];
#pragma unroll
      for (int i = 0; i < 8; i++)
#pragma unroll
        for (int j = 0; j < 8; j++) acc[i][j] += a[i] * b[j];
    }
  }
#pragma unroll
  for (int i = 0; i < 8; i++)
#pragma unroll
    for (int j = 0; j < 8; j++)
      atomicAdd(&upd[((size_t)h * HD + tr * 8 + i) * HD + tc * 8 + j], acc[i][j]);
}

// ---- K9: column sum of sigma_k -> colsum[2048] ----
__global__ __launch_bounds__(256) void colsum_kernel(const unsigned short* __restrict__ sk,
                                                     float* __restrict__ colsum) {
  int b = blockIdx.x;  // 256 blocks x 64 tokens
  int tid = threadIdx.x;
  float acc[8] = {};
  for (int t = b * 64; t < b * 64 + 64; t++) {
    const unsigned short* p = sk + (size_t)t * HIDN;
#pragma unroll
    for (int j = 0; j < 8; j++) acc[j] += bf2f(p[tid + j * 256]);
  }
#pragma unroll
  for (int j = 0; j < 8; j++) atomicAdd(&colsum[tid + j * 256], acc[j]);
}

// ---- K10: write new_mem0 and new_norm0 ----
__global__ __launch_bounds__(256) void finalize_kernel(
    const float* __restrict__ mem, const float* __restrict__ mnorm,
    const float* __restrict__ upd, const float* __restrict__ colsum,
    float* __restrict__ out_mem, float* __restrict__ out_norm) {
  int i = blockIdx.x * 256 + threadIdx.x;  // 262144 threads
  if (i < NH * HD * HD) out_mem[i] = mem[i] + upd[i] * (1.f / 16384.f);
  if (i < HIDN) out_norm[i] = mnorm[i] + colsum[i] * 0.25f;
}

extern "C" void kernel_launch(void* const* d_in, const int* in_sizes, int n_in,
                              void* d_out, int out_size, void* d_ws, size_t ws_size,
                              hipStream_t stream) {
  (void)in_sizes; (void)n_in; (void)out_size; (void)ws_size;
  const float* hidden = (const float*)d_in[0];
  const float* Wq = (const float*)d_in[1];
  const float* Wk = (const float*)d_in[2];
  const float* Wv = (const float*)d_in[3];
  const float* Wo = (const float*)d_in[4];
  const float* bw = (const float*)d_in[5];
  const float* mem = (const float*)d_in[6];
  const float* mnorm = (const float*)d_in[7];

  float* out = (float*)d_out;
  float* out_mem = out + (size_t)NTOK * HIDN;
  float* out_norm = out_mem + NH * HD * HD;

  char* w = (char*)d_ws;
  size_t off = 0;
  auto alloc = [&](size_t bytes) {
    char* p = w + off;
    off += (bytes + 255) & ~(size_t)255;
    return p;
  };
  unsigned short* Xb    = (unsigned short*)alloc((size_t)NTOK * HIDN * 2);  // reused as comb
  unsigned short* Wqkvb = (unsigned short*)alloc((size_t)3 * HIDN * HIDN * 2);
  unsigned short* Wob   = (unsigned short*)alloc((size_t)HIDN * HIDN * 2);
  unsigned short* sq    = (unsigned short*)alloc((size_t)NTOK * HIDN * 2);
  unsigned short* sk    = (unsigned short*)alloc((size_t)NTOK * HIDN * 2);
  unsigned short* vb    = (unsigned short*)alloc((size_t)NTOK * HIDN * 2);
  unsigned short* dvb   = (unsigned short*)alloc((size_t)NTOK * HIDN * 2);
  float* cbuf   = (float*)alloc((size_t)NTOK * NH * 4 * 4);
  float* knorm  = (float*)alloc((size_t)NTOK * NH * 4);
  float* wact   = (float*)alloc(256);
  unsigned short* membT = (unsigned short*)alloc((size_t)NB * NH * HD * HD * 2);
  float* upd    = (float*)alloc((size_t)NH * HD * HD * 4);
  float* colsum = (float*)alloc(HIDN * 4);
  unsigned short* comb = Xb;  // Xb dead after QKV GEMM; alias

  (void)hipMemsetAsync(upd, 0, (size_t)NH * HD * HD * 4, stream);
  (void)hipMemsetAsync(colsum, 0, HIDN * 4, stream);

  prep_kernel<<<1, 64, 0, stream>>>(bw, mnorm, wact);
  cast_bf16_kernel<<<NTOK * HIDN / 8 / 256, 256, 0, stream>>>(hidden, Xb, NTOK * HIDN / 8);
  cast_bf16_kernel<<<HIDN * HIDN / 8 / 256, 256, 0, stream>>>(Wq, Wqkvb, HIDN * HIDN / 8);
  cast_bf16_kernel<<<HIDN * HIDN / 8 / 256, 256, 0, stream>>>(Wk, Wqkvb + (size_t)HIDN * HIDN, HIDN * HIDN / 8);
  cast_bf16_kernel<<<HIDN * HIDN / 8 / 256, 256, 0, stream>>>(Wv, Wqkvb + (size_t)2 * HIDN * HIDN, HIDN * HIDN / 8);
  cast_bf16_kernel<<<HIDN * HIDN / 8 / 256, 256, 0, stream>>>(Wo, Wob, HIDN * HIDN / 8);
  mem_transpose_kernel<<<NB * NH, 256, 0, stream>>>(mem, membT);

  // QKV: [16384,2048] x [6144,2048]^T -> sigma_q, sigma_k, v (bf16)
  gemm_nt_kernel<0><<<dim3(NTOK / 128, 3 * HIDN / 128), 256, 0, stream>>>(
      Xb, Wqkvb, HIDN, 3 * HIDN, sq, sk, vb, nullptr);

  coeff_kernel<<<NTOK * NH / 256, 256, 0, stream>>>(sq, sk, mnorm, wact, cbuf, knorm);
  retrieve_kernel<<<dim3(NTOK / 64, NH), 256, 0, stream>>>(sq, membT, cbuf, comb);
  delta_kernel<<<dim3(NTOK / 64, NH), 256, 0, stream>>>(sk, membT, vb, knorm, dvb);
  memupd_kernel<<<dim3(NH, 32), 256, 0, stream>>>(sk, dvb, upd);
  colsum_kernel<<<NTOK / 64, 256, 0, stream>>>(sk, colsum);
  finalize_kernel<<<NH * HD * HD / 256, 256, 0, stream>>>(mem, mnorm, upd, colsum, out_mem, out_norm);

  // out = combined @ Wo^T -> fp32 d_out
  gemm_nt_kernel<1><<<dim3(NTOK / 128, HIDN / 128), 256, 0, stream>>>(
      comb, Wob, HIDN, HIDN, nullptr, nullptr, nullptr, out);
}

// Round 3
// 1602.985 us; speedup vs baseline: 1.1818x; 1.1818x over previous
//
#include <hip/hip_runtime.h>
#include <cstdint>
#include <cstddef>

// ---- problem constants ----
#define NTOK 16384     // B*S = 4*4096
#define HIDN 2048
#define NH   16
#define HD   128
#define NB   4
#define EPSF 1e-6f

typedef __attribute__((ext_vector_type(8))) short bvec8;   // 8 bf16 (4 VGPRs)
typedef __attribute__((ext_vector_type(4))) float fvec4;   // MFMA accumulator

// Wave-uniform-base async global->LDS, 16B per lane. lp MUST be the wave's
// base (lane0 chunk); HW writes lane L at lp + L*16 [m104/m108].
#define GLOAD_LDS16(gp, lp)                                                     \
  __builtin_amdgcn_global_load_lds(                                             \
      (const __attribute__((address_space(1))) void*)(gp),                      \
      (__attribute__((address_space(3))) void*)(lp), 16, 0, 0)

__device__ __forceinline__ unsigned short f2bf(float x) {
  union { float f; uint32_t u; } v; v.f = x;
  uint32_t r = (v.u + 0x7fffu + ((v.u >> 16) & 1u)) >> 16;  // RNE
  return (unsigned short)r;
}
__device__ __forceinline__ float bf2f(unsigned short b) {
  union { uint32_t u; float f; } v; v.u = ((uint32_t)b) << 16;
  return v.f;
}
__device__ __forceinline__ float elu1(float x) { return x > 0.f ? x + 1.f : __expf(x); }

// ---- K0: softmax(bank_weights)*active -> wact[h*4+n] ----
__global__ void prep_kernel(const float* __restrict__ bw, const float* __restrict__ mnorm,
                            float* __restrict__ wact) {
  __shared__ float acc[NB];
  int tid = threadIdx.x;  // 64 threads
  if (tid < NB) acc[tid] = 0.f;
  __syncthreads();
  {
    int n = tid & 3, part = tid >> 2;  // 16 partial sums per bank
    float s = 0.f;
    for (int i = part; i < NH * HD; i += 16) s += mnorm[n * NH * HD + i];
    atomicAdd(&acc[n], s);
  }
  __syncthreads();
  int h = tid >> 2, n = tid & 3;
  float w0 = bw[h*4+0], w1 = bw[h*4+1], w2 = bw[h*4+2], w3 = bw[h*4+3];
  float mx = fmaxf(fmaxf(w0, w1), fmaxf(w2, w3));
  float e0 = __expf(w0-mx), e1 = __expf(w1-mx), e2 = __expf(w2-mx), e3 = __expf(w3-mx);
  float sum = e0 + e1 + e2 + e3;
  float en = (n == 0) ? e0 : ((n == 1) ? e1 : ((n == 2) ? e2 : e3));
  float act = (acc[n] >= EPSF) ? 1.f : 0.f;
  wact[tid] = (en / sum) * act;
}

// ---- K1: fp32 -> bf16 cast, 8 elems/thread ----
__global__ __launch_bounds__(256) void cast_bf16_kernel(const float* __restrict__ src,
                                                        unsigned short* __restrict__ dst, int n8) {
  int i = blockIdx.x * 256 + threadIdx.x;
  if (i >= n8) return;
  const float4* s = (const float4*)src + (size_t)i * 2;
  float4 a = s[0], b = s[1];
  uint32_t p0 = (uint32_t)f2bf(a.x) | ((uint32_t)f2bf(a.y) << 16);
  uint32_t p1 = (uint32_t)f2bf(a.z) | ((uint32_t)f2bf(a.w) << 16);
  uint32_t p2 = (uint32_t)f2bf(b.x) | ((uint32_t)f2bf(b.y) << 16);
  uint32_t p3 = (uint32_t)f2bf(b.z) | ((uint32_t)f2bf(b.w) << 16);
  uint4 o; o.x = p0; o.y = p1; o.z = p2; o.w = p3;
  *(uint4*)(dst + (size_t)i * 8) = o;
}

// ---- K1b: memories[n,h,d,e] -> bf16 transposed membT[n,h,e,d] ----
__global__ __launch_bounds__(256) void mem_transpose_kernel(const float* __restrict__ mem,
                                                            unsigned short* __restrict__ membT) {
  int nh = blockIdx.x;  // 64 blocks
  const float* src = mem + (size_t)nh * (HD * HD);
  unsigned short* dst = membT + (size_t)nh * (HD * HD);
  for (int i = threadIdx.x; i < HD * HD; i += 256) {
    int d = i >> 7, e = i & 127;
    dst[e * HD + d] = f2bf(src[i]);
  }
}

// ---- K2/K11: NT GEMM, m97 structure: 128x128 tile, BK=32 unpadded, global_load_lds w16 ----
// C[i,j] = sum_k A[i,k]*B[j,k].  MODE 0: QKV epilogue (elu+1 on q,k; bf16 out to 3 bufs)
//                                MODE 1: fp32 C out (ld = N)
template<int MODE>
__global__ __launch_bounds__(256) void gemm_nt_kernel(
    const unsigned short* __restrict__ A, const unsigned short* __restrict__ B,
    int K, int N,
    unsigned short* __restrict__ oq, unsigned short* __restrict__ ok,
    unsigned short* __restrict__ ov, float* __restrict__ oc) {
  __shared__ __align__(16) unsigned short As[128 * 32];  // unpadded, 64B row stride (m97 geometry)
  __shared__ __align__(16) unsigned short Bs[128 * 32];
  const int tid = threadIdx.x;
  const int wave = tid >> 6, lane = tid & 63;
  const int lr = lane & 15, lq = lane >> 4;
  const int wr = (wave >> 1) * 64, wc = (wave & 1) * 64;
  const int bm = blockIdx.x, bn = blockIdx.y;
  const size_t arow0 = (size_t)bm * 128;
  const size_t brow0 = (size_t)bn * 128;
  fvec4 acc[4][4] = {};
  for (int k0 = 0; k0 < K; k0 += 32) {
    __syncthreads();  // previous iter's ds_reads done before overwrite
#pragma unroll
    for (int p = 0; p < 2; p++) {  // 512 chunks of 16B per buffer, 2 per thread
      int c = p * 256 + tid;
      int row = c >> 2, j = c & 3;
      int cb = __builtin_amdgcn_readfirstlane(c);  // wave-uniform chunk base (lane0's c)
      GLOAD_LDS16(A + (arow0 + row) * K + k0 + j * 8, As + (size_t)cb * 8);
      GLOAD_LDS16(B + (brow0 + row) * K + k0 + j * 8, Bs + (size_t)cb * 8);
    }
    __syncthreads();  // barrier drains vmcnt -> LDS visible
    bvec8 af[4], bfr[4];
#pragma unroll
    for (int mi = 0; mi < 4; mi++)
      af[mi] = *(const bvec8*)(As + (wr + mi * 16 + lr) * 32 + lq * 8);
#pragma unroll
    for (int ni = 0; ni < 4; ni++)
      bfr[ni] = *(const bvec8*)(Bs + (wc + ni * 16 + lr) * 32 + lq * 8);
#pragma unroll
    for (int mi = 0; mi < 4; mi++)
#pragma unroll
      for (int ni = 0; ni < 4; ni++)
        acc[mi][ni] = __builtin_amdgcn_mfma_f32_16x16x32_bf16(af[mi], bfr[ni], acc[mi][ni], 0, 0, 0);
  }
  // epilogue: D row = (lane>>4)*4 + reg, col = lane&15  [measured m89/m91]
#pragma unroll
  for (int mi = 0; mi < 4; mi++) {
#pragma unroll
    for (int ni = 0; ni < 4; ni++) {
#pragma unroll
      for (int r = 0; r < 4; r++) {
        int grow = bm * 128 + wr + mi * 16 + lq * 4 + r;
        int gcol = bn * 128 + wc + ni * 16 + lr;
        float v = acc[mi][ni][r];
        if (MODE == 0) {
          int seg = gcol >> 11;  // 0:q 1:k 2:v
          int col = gcol & 2047;
          unsigned short* dst = (seg == 0) ? oq : ((seg == 1) ? ok : ov);
          float t = (seg < 2) ? elu1(v) : v;
          dst[(size_t)grow * HIDN + col] = f2bf(t);
        } else {
          oc[(size_t)grow * N + gcol] = v;
        }
      }
    }
  }
}

// ---- K5: per-(token,head) bank coefficients + knorm (vectorized) ----
__global__ __launch_bounds__(256) void coeff_kernel(
    const unsigned short* __restrict__ sq, const unsigned short* __restrict__ sk,
    const float* __restrict__ mnorm, const float* __restrict__ wact,
    float* __restrict__ cbuf, float* __restrict__ knorm) {
  int g = blockIdx.x * 256 + threadIdx.x;  // 262144 = T*NH
  int t = g >> 4, h = g & 15;
  const unsigned short* qp = sq + (size_t)t * HIDN + h * HD;
  const unsigned short* kp = sk + (size_t)t * HIDN + h * HD;
  const float* m0 = mnorm + (0 * NH + h) * HD;
  const float* m1 = mnorm + (1 * NH + h) * HD;
  const float* m2 = mnorm + (2 * NH + h) * HD;
  const float* m3 = mnorm + (3 * NH + h) * HD;
  float n0 = 0, n1 = 0, n2 = 0, n3 = 0, kn = 0;
#pragma unroll 4
  for (int i = 0; i < HD; i += 8) {
    uint4 qv4 = *(const uint4*)(qp + i);
    uint4 kv4 = *(const uint4*)(kp + i);
    const uint32_t qw[4] = {qv4.x, qv4.y, qv4.z, qv4.w};
    const uint32_t kw[4] = {kv4.x, kv4.y, kv4.z, kv4.w};
#pragma unroll
    for (int j = 0; j < 4; j++) {
      float q0 = bf2f((unsigned short)(qw[j] & 0xffff));
      float q1 = bf2f((unsigned short)(qw[j] >> 16));
      float k0 = bf2f((unsigned short)(kw[j] & 0xffff));
      float k1 = bf2f((unsigned short)(kw[j] >> 16));
      int i0 = i + j * 2, i1 = i + j * 2 + 1;
      n0 += q0 * m0[i0] + q1 * m0[i1];
      n1 += q0 * m1[i0] + q1 * m1[i1];
      n2 += q0 * m2[i0] + q1 * m2[i1];
      n3 += q0 * m3[i0] + q1 * m3[i1];
      kn += k0 * m0[i0] + k1 * m0[i1];
    }
  }
  cbuf[(size_t)g * 4 + 0] = wact[h * 4 + 0] / fmaxf(n0, EPSF);
  cbuf[(size_t)g * 4 + 1] = wact[h * 4 + 1] / fmaxf(n1, EPSF);
  cbuf[(size_t)g * 4 + 2] = wact[h * 4 + 2] / fmaxf(n2, EPSF);
  cbuf[(size_t)g * 4 + 3] = wact[h * 4 + 3] / fmaxf(n3, EPSF);
  knorm[g] = fmaxf(kn, EPSF);
}

// ---- K6: retrieval. block = (64-token tile, head); 4 banks, scale by c, sum -> combined ----
// LDS panels [kc][rows][32] keep chunk index linear in tid for global_load_lds.
__global__ __launch_bounds__(256) void retrieve_kernel(
    const unsigned short* __restrict__ sq, const unsigned short* __restrict__ membT,
    const float* __restrict__ cbuf, unsigned short* __restrict__ comb) {
  __shared__ __align__(16) unsigned short Sq[4 * 64 * 32];    // 16 KB
  __shared__ __align__(16) unsigned short Mt[4 * 128 * 32];   // 32 KB
  __shared__ float ct[64 * 4];
  const int tb = blockIdx.x, h = blockIdx.y;
  const int tid = threadIdx.x;
  const int wave = tid >> 6, lane = tid & 63;
  const int lr = lane & 15, lq = lane >> 4;
  const int wr = (wave >> 1) * 32, wc = (wave & 1) * 64;
#pragma unroll
  for (int p = 0; p < 4; p++) {  // Sq: 64x128 bf16 = 1024 chunks
    int c = p * 256 + tid;
    int kc = c >> 8, r = (c >> 2) & 63, j = c & 3;
    int cb = __builtin_amdgcn_readfirstlane(c);
    GLOAD_LDS16(sq + (size_t)(tb * 64 + r) * HIDN + h * HD + kc * 32 + j * 8,
                Sq + (size_t)cb * 8);
  }
  {
    int tl = tid >> 2, n = tid & 3;
    ct[tid] = cbuf[(((size_t)(tb * 64 + tl)) * NH + h) * 4 + n];
  }
  float wacc[2][4][4] = {};
  for (int n = 0; n < NB; n++) {
    __syncthreads();  // prior-bank Mt reads done before overwrite
    const unsigned short* msrc = membT + (size_t)(n * NH + h) * (HD * HD);
#pragma unroll
    for (int p = 0; p < 8; p++) {  // Mt: 128x128 bf16 = 2048 chunks
      int c = p * 256 + tid;
      int kc = c >> 9, r = (c >> 2) & 127, j = c & 3;
      int cb = __builtin_amdgcn_readfirstlane(c);
      GLOAD_LDS16(msrc + r * HD + kc * 32 + j * 8, Mt + (size_t)cb * 8);
    }
    __syncthreads();  // vmcnt drained -> Sq (n=0) and Mt visible
    fvec4 u[2][4] = {};
#pragma unroll
    for (int dk = 0; dk < HD; dk += 32) {
      int kc = dk >> 5;
      bvec8 af[2], bfr[4];
#pragma unroll
      for (int mi = 0; mi < 2; mi++)
        af[mi] = *(const bvec8*)(Sq + (kc * 64 + wr + mi * 16 + lr) * 32 + lq * 8);
#pragma unroll
      for (int ni = 0; ni < 4; ni++)
        bfr[ni] = *(const bvec8*)(Mt + (kc * 128 + wc + ni * 16 + lr) * 32 + lq * 8);
#pragma unroll
      for (int mi = 0; mi < 2; mi++)
#pragma unroll
        for (int ni = 0; ni < 4; ni++)
          u[mi][ni] = __builtin_amdgcn_mfma_f32_16x16x32_bf16(af[mi], bfr[ni], u[mi][ni], 0, 0, 0);
    }
#pragma unroll
    for (int mi = 0; mi < 2; mi++)
#pragma unroll
      for (int ni = 0; ni < 4; ni++)
#pragma unroll
        for (int r = 0; r < 4; r++) {
          int rl = wr + mi * 16 + lq * 4 + r;
          wacc[mi][ni][r] += ct[rl * 4 + n] * u[mi][ni][r];
        }
  }
#pragma unroll
  for (int mi = 0; mi < 2; mi++)
#pragma unroll
    for (int ni = 0; ni < 4; ni++)
#pragma unroll
      for (int r = 0; r < 4; r++) {
        int rl = wr + mi * 16 + lq * 4 + r;
        int col = h * HD + wc + ni * 16 + lr;
        comb[(size_t)(tb * 64 + rl) * HIDN + col] = f2bf(wacc[mi][ni][r]);
      }
}

// ---- K7: delta_v = v - (sigma_k @ mem0)/knorm, bf16 out ----
__global__ __launch_bounds__(256) void delta_kernel(
    const unsigned short* __restrict__ sk, const unsigned short* __restrict__ membT,
    const unsigned short* __restrict__ vb, const float* __restrict__ knorm,
    unsigned short* __restrict__ dv) {
  __shared__ __align__(16) unsigned short Sk[4 * 64 * 32];
  __shared__ __align__(16) unsigned short Mt[4 * 128 * 32];
  const int tb = blockIdx.x, h = blockIdx.y;
  const int tid = threadIdx.x;
  const int wave = tid >> 6, lane = tid & 63;
  const int lr = lane & 15, lq = lane >> 4;
  const int wr = (wave >> 1) * 32, wc = (wave & 1) * 64;
#pragma unroll
  for (int p = 0; p < 4; p++) {
    int c = p * 256 + tid;
    int kc = c >> 8, r = (c >> 2) & 63, j = c & 3;
    int cb = __builtin_amdgcn_readfirstlane(c);
    GLOAD_LDS16(sk + (size_t)(tb * 64 + r) * HIDN + h * HD + kc * 32 + j * 8,
                Sk + (size_t)cb * 8);
  }
  const unsigned short* msrc = membT + (size_t)h * (HD * HD);  // bank 0
#pragma unroll
  for (int p = 0; p < 8; p++) {
    int c = p * 256 + tid;
    int kc = c >> 9, r = (c >> 2) & 127, j = c & 3;
    int cb = __builtin_amdgcn_readfirstlane(c);
    GLOAD_LDS16(msrc + r * HD + kc * 32 + j * 8, Mt + (size_t)cb * 8);
  }
  __syncthreads();
  fvec4 u[2][4] = {};
#pragma unroll
  for (int dk = 0; dk < HD; dk += 32) {
    int kc = dk >> 5;
    bvec8 af[2], bfr[4];
#pragma unroll
    for (int mi = 0; mi < 2; mi++)
      af[mi] = *(const bvec8*)(Sk + (kc * 64 + wr + mi * 16 + lr) * 32 + lq * 8);
#pragma unroll
    for (int ni = 0; ni < 4; ni++)
      bfr[ni] = *(const bvec8*)(Mt + (kc * 128 + wc + ni * 16 + lr) * 32 + lq * 8);
#pragma unroll
    for (int mi = 0; mi < 2; mi++)
#pragma unroll
      for (int ni = 0; ni < 4; ni++)
        u[mi][ni] = __builtin_amdgcn_mfma_f32_16x16x32_bf16(af[mi], bfr[ni], u[mi][ni], 0, 0, 0);
  }
#pragma unroll
  for (int mi = 0; mi < 2; mi++)
#pragma unroll
    for (int ni = 0; ni < 4; ni++)
#pragma unroll
      for (int r = 0; r < 4; r++) {
        int rl = wr + mi * 16 + lq * 4 + r;
        int t = tb * 64 + rl;
        int e = wc + ni * 16 + lr;
        float kn = knorm[(size_t)t * NH + h];
        float vv = bf2f(vb[(size_t)t * HIDN + h * HD + e]);
        dv[(size_t)t * HIDN + h * HD + e] = f2bf(vv - u[mi][ni][r] / kn);
      }
}

// ---- K8: mem_update partial: upd[h,d,e] += sum_t sigma_k[t,d]*dv[t,e] (split-K, atomics) ----
__global__ __launch_bounds__(256) void memupd_kernel(const unsigned short* __restrict__ sk,
                                                     const unsigned short* __restrict__ dv,
                                                     float* __restrict__ upd) {
  const int h = blockIdx.x, kc = blockIdx.y;  // 16 x 32, 512 tokens per chunk
  __shared__ float sA[8][128], sB[8][128];
  const int tid = threadIdx.x;
  const int tr = tid >> 4, tc = tid & 15;  // thread owns d in [tr*8,+8), e in [tc*8,+8)
  float acc[8][8] = {};
  for (int t0 = kc * 512; t0 < kc * 512 + 512; t0 += 8) {
    __syncthreads();
    int row = tid >> 5, col = (tid & 31) * 4;
    const unsigned short* ap = sk + (size_t)(t0 + row) * HIDN + h * HD + col;
    const unsigned short* bp = dv + (size_t)(t0 + row) * HIDN + h * HD + col;
    ushort4 av = *(const ushort4*)ap;
    ushort4 bv = *(const ushort4*)bp;
    sA[row][col + 0] = bf2f(av.x); sA[row][col + 1] = bf2f(av.y);
    sA[row][col + 2] = bf2f(av.z); sA[row][col + 3] = bf2f(av.w);
    sB[row][col + 0] = bf2f(bv.x); sB[row][col + 1] = bf2f(bv.y);
    sB[row][col + 2] = bf2f(bv.z); sB[row][col + 3] = bf2f(bv.w);
    __syncthreads();
#pragma unroll
    for (int tt = 0; tt < 8; tt++) {
      float a[8], b[8];
#pragma unroll
      for (int i = 0; i < 8; i++) a[i] = sA[tt][tr * 8 + i];
#pragma unroll
      for (int j = 0; j < 8; j++) b[j] = sB[tt][tc * 8 + j];
#pragma unroll
      for (int i = 0; i < 8; i++)
#pragma unroll
        for (int j = 0; j < 8; j++) acc[i][j] += a[i] * b[j];
    }
  }
#pragma unroll
  for (int i = 0; i < 8; i++)
#pragma unroll
    for (int j = 0; j < 8; j++)
      atomicAdd(&upd[((size_t)h * HD + tr * 8 + i) * HD + tc * 8 + j], acc[i][j]);
}

// ---- K9: column sum of sigma_k -> colsum[2048] ----
__global__ __launch_bounds__(256) void colsum_kernel(const unsigned short* __restrict__ sk,
                                                     float* __restrict__ colsum) {
  int b = blockIdx.x;  // 256 blocks x 64 tokens
  int tid = threadIdx.x;
  float acc[8] = {};
  for (int t = b * 64; t < b * 64 + 64; t++) {
    const unsigned short* p = sk + (size_t)t * HIDN;
#pragma unroll
    for (int j = 0; j < 8; j++) acc[j] += bf2f(p[tid + j * 256]);
  }
#pragma unroll
  for (int j = 0; j < 8; j++) atomicAdd(&colsum[tid + j * 256], acc[j]);
}

// ---- K10: write new_mem0 and new_norm0 ----
__global__ __launch_bounds__(256) void finalize_kernel(
    const float* __restrict__ mem, const float* __restrict__ mnorm,
    const float* __restrict__ upd, const float* __restrict__ colsum,
    float* __restrict__ out_mem, float* __restrict__ out_norm) {
  int i = blockIdx.x * 256 + threadIdx.x;  // 262144 threads
  if (i < NH * HD * HD) out_mem[i] = mem[i] + upd[i] * (1.f / 16384.f);
  if (i < HIDN) out_norm[i] = mnorm[i] + colsum[i] * 0.25f;
}

extern "C" void kernel_launch(void* const* d_in, const int* in_sizes, int n_in,
                              void* d_out, int out_size, void* d_ws, size_t ws_size,
                              hipStream_t stream) {
  (void)in_sizes; (void)n_in; (void)out_size; (void)ws_size;
  const float* hidden = (const float*)d_in[0];
  const float* Wq = (const float*)d_in[1];
  const float* Wk = (const float*)d_in[2];
  const float* Wv = (const float*)d_in[3];
  const float* Wo = (const float*)d_in[4];
  const float* bw = (const float*)d_in[5];
  const float* mem = (const float*)d_in[6];
  const float* mnorm = (const float*)d_in[7];

  float* out = (float*)d_out;
  float* out_mem = out + (size_t)NTOK * HIDN;
  float* out_norm = out_mem + NH * HD * HD;

  char* w = (char*)d_ws;
  size_t off = 0;
  auto alloc = [&](size_t bytes) {
    char* p = w + off;
    off += (bytes + 255) & ~(size_t)255;
    return p;
  };
  unsigned short* Xb    = (unsigned short*)alloc((size_t)NTOK * HIDN * 2);  // reused as comb
  unsigned short* Wqkvb = (unsigned short*)alloc((size_t)3 * HIDN * HIDN * 2);
  unsigned short* Wob   = (unsigned short*)alloc((size_t)HIDN * HIDN * 2);
  unsigned short* sq    = (unsigned short*)alloc((size_t)NTOK * HIDN * 2);
  unsigned short* sk    = (unsigned short*)alloc((size_t)NTOK * HIDN * 2);
  unsigned short* vb    = (unsigned short*)alloc((size_t)NTOK * HIDN * 2);
  unsigned short* dvb   = (unsigned short*)alloc((size_t)NTOK * HIDN * 2);
  float* cbuf   = (float*)alloc((size_t)NTOK * NH * 4 * 4);
  float* knorm  = (float*)alloc((size_t)NTOK * NH * 4);
  float* wact   = (float*)alloc(256);
  unsigned short* membT = (unsigned short*)alloc((size_t)NB * NH * HD * HD * 2);
  float* upd    = (float*)alloc((size_t)NH * HD * HD * 4);
  float* colsum = (float*)alloc(HIDN * 4);
  unsigned short* comb = Xb;  // Xb dead after QKV GEMM; alias

  (void)hipMemsetAsync(upd, 0, (size_t)NH * HD * HD * 4, stream);
  (void)hipMemsetAsync(colsum, 0, HIDN * 4, stream);

  prep_kernel<<<1, 64, 0, stream>>>(bw, mnorm, wact);
  cast_bf16_kernel<<<NTOK * HIDN / 8 / 256, 256, 0, stream>>>(hidden, Xb, NTOK * HIDN / 8);
  cast_bf16_kernel<<<HIDN * HIDN / 8 / 256, 256, 0, stream>>>(Wq, Wqkvb, HIDN * HIDN / 8);
  cast_bf16_kernel<<<HIDN * HIDN / 8 / 256, 256, 0, stream>>>(Wk, Wqkvb + (size_t)HIDN * HIDN, HIDN * HIDN / 8);
  cast_bf16_kernel<<<HIDN * HIDN / 8 / 256, 256, 0, stream>>>(Wv, Wqkvb + (size_t)2 * HIDN * HIDN, HIDN * HIDN / 8);
  cast_bf16_kernel<<<HIDN * HIDN / 8 / 256, 256, 0, stream>>>(Wo, Wob, HIDN * HIDN / 8);
  mem_transpose_kernel<<<NB * NH, 256, 0, stream>>>(mem, membT);

  // QKV: [16384,2048] x [6144,2048]^T -> sigma_q, sigma_k, v (bf16)
  gemm_nt_kernel<0><<<dim3(NTOK / 128, 3 * HIDN / 128), 256, 0, stream>>>(
      Xb, Wqkvb, HIDN, 3 * HIDN, sq, sk, vb, nullptr);

  coeff_kernel<<<NTOK * NH / 256, 256, 0, stream>>>(sq, sk, mnorm, wact, cbuf, knorm);
  retrieve_kernel<<<dim3(NTOK / 64, NH), 256, 0, stream>>>(sq, membT, cbuf, comb);
  delta_kernel<<<dim3(NTOK / 64, NH), 256, 0, stream>>>(sk, membT, vb, knorm, dvb);
  memupd_kernel<<<dim3(NH, 32), 256, 0, stream>>>(sk, dvb, upd);
  colsum_kernel<<<NTOK / 64, 256, 0, stream>>>(sk, colsum);
  finalize_kernel<<<NH * HD * HD / 256, 256, 0, stream>>>(mem, mnorm, upd, colsum, out_mem, out_norm);

  // out = combined @ Wo^T -> fp32 d_out
  gemm_nt_kernel<1><<<dim3(NTOK / 128, HIDN / 128), 256, 0, stream>>>(
      comb, Wob, HIDN, HIDN, nullptr, nullptr, nullptr, out);
}